// Round 8
// baseline (126.290 us; speedup 1.0000x reference)
//
#include <hip/hip_runtime.h>

// GeometricLoss: N=8192 2-D points, C=16 outputs, k=5 nearest neighbors,
// result = mean over (i, 5 NN j) of ||outputs[i]-outputs[j]||_2.
//
// Round-8 structure: 512 threads/block, QPB=8 queries per block, 1024
// blocks (= 8192 waves, 32/CU). Each thread loads its 8 candidate float4
// ONCE into registers; pass 1 (per-thread per-query raw-d2 min via min3)
// and pass 2 (rare threshold collect) both run from those registers ->
// only ONE 64 KB stream of points per block (67 MB L2 total) and zero
// pass-2 load latency. Queries and thresholds are block-uniform ->
// pinned to SGPRs via readfirstlane.
// T_q = 6th-distinct-smallest of 64 lane pre-mins (each lane pre-mins 8
// threads' clamped minima over disjoint candidate subsets) -> >=6
// candidates <= T_q guaranteed. Pass 2 recomputes d2 with the IDENTICAL
// fmaf sequence (bit-exact) and collects (clamped-d2, j) u64 keys
// ((bits<<32)|j) into per-query LDS buffers; wave w then extracts the 6
// smallest keys for query w (replicating top_k's smaller-index
// tie-break), drops the first (self), lanes 1..5 compute neighbor norms.

static constexpr int NPTS    = 8192;
static constexpr int KNN     = 5;
static constexpr int CH      = 16;
static constexpr int QPB     = 8;                 // queries per block (= waves)
static constexpr int THREADS = 512;
static constexpr int NBLK    = NPTS / QPB;        // 1024 blocks
static constexpr int CAP     = 128;               // per-query candidate buffer
static constexpr int NF4     = NPTS / 2;          // 4096 float4 = 2 points each
static constexpr int ITERS   = NF4 / THREADS;     // 8 float4 per thread

__device__ __forceinline__ unsigned long long shfl_xor_u64(unsigned long long v, int m) {
    unsigned int lo = (unsigned int)v;
    unsigned int hi = (unsigned int)(v >> 32);
    lo = __shfl_xor(lo, m, 64);
    hi = __shfl_xor(hi, m, 64);
    return ((unsigned long long)hi << 32) | lo;
}

__device__ __forceinline__ float rfl(float x) {   // force block-uniform -> SGPR
    return __uint_as_float(__builtin_amdgcn_readfirstlane(__float_as_uint(x)));
}

__global__ __launch_bounds__(512, 8) void knn_loss_kernel(
        const float* __restrict__ outputs,
        const float* __restrict__ points,
        float* __restrict__ partial) {
    const int tid   = threadIdx.x;
    const int wave  = tid >> 6;
    const int lane  = tid & 63;
    const int qbase = blockIdx.x * QPB;

    const float2* __restrict__ pts2 = (const float2*)points;
    const float4* __restrict__ pts4 = (const float4*)points;
    const float FINF = __int_as_float(0x7f800000);

    float pix[QPB], piy[QPB];
    #pragma unroll
    for (int q = 0; q < QPB; ++q) {
        const float2 pq = pts2[qbase + q];
        pix[q] = rfl(pq.x); piy[q] = rfl(pq.y);
    }

    // ---- Load this thread's 8 candidate float4 ONCE; keep live in VGPRs ----
    float4 p[ITERS];
    #pragma unroll
    for (int u = 0; u < ITERS; ++u)
        p[u] = pts4[u * THREADS + tid];

    // ---- Pass 1: per-thread per-query min of raw d2 (branchless min3) ----
    float acc[QPB];
    #pragma unroll
    for (int q = 0; q < QPB; ++q) acc[q] = FINF;
    #pragma unroll
    for (int u = 0; u < ITERS; ++u) {
        #pragma unroll
        for (int q = 0; q < QPB; ++q) {
            const float dxa = pix[q] - p[u].x, dya = piy[q] - p[u].y;
            const float dxb = pix[q] - p[u].z, dyb = piy[q] - p[u].w;
            const float d2a = fmaf(dxa, dxa, dya * dya);
            const float d2b = fmaf(dxb, dxb, dyb * dyb);
            acc[q] = fminf(fminf(acc[q], d2a), d2b);   // v_min3
        }
    }

    // ---- Block thresholds: T_q = 6th-distinct-smallest of 64 lane pre-mins ----
    __shared__ float thrmin[QPB][THREADS];
    __shared__ unsigned long long buf[QPB][CAP];
    __shared__ int cnt[QPB];
    __shared__ float Ts[QPB];
    __shared__ float red[QPB];

    #pragma unroll
    for (int q = 0; q < QPB; ++q)
        thrmin[q][tid] = fmaxf(acc[q], 0.0f);          // clamped per-thread min
    if (tid < QPB) cnt[tid] = 0;
    __syncthreads();

    {   // wave w handles query w; stride-64 reads are bank-conflict-free
        float v = thrmin[wave][lane];
        #pragma unroll
        for (int r = 1; r < THREADS / 64; ++r)
            v = fminf(v, thrmin[wave][lane + r * 64]);
        float T = 0.0f;
        #pragma unroll
        for (int t = 0; t < KNN + 1; ++t) {
            float m = v;
            #pragma unroll
            for (int d = 1; d < 64; d <<= 1) m = fminf(m, __shfl_xor(m, d, 64));
            if (v == m) v = FINF;
            T = m;
        }
        if (lane == 0) Ts[wave] = T;
    }
    __syncthreads();

    float Tq[QPB];
    #pragma unroll
    for (int q = 0; q < QPB; ++q) Tq[q] = rfl(Ts[q]);  // SGPR

    // ---- Pass 2: pure-register recompute, rare per-query collect ----
    #pragma unroll
    for (int u = 0; u < ITERS; ++u) {
        const int jpair = u * THREADS + tid;           // float4 index
        #pragma unroll
        for (int q = 0; q < QPB; ++q) {
            const float dxa = pix[q] - p[u].x, dya = piy[q] - p[u].y;
            const float dxb = pix[q] - p[u].z, dyb = piy[q] - p[u].w;
            const float d2a = fmaf(dxa, dxa, dya * dya);
            const float d2b = fmaf(dxb, dxb, dyb * dyb);
            if (fminf(d2a, d2b) <= Tq[q]) {            // rare: execz skip
                if (d2a <= Tq[q]) {
                    const int pos = atomicAdd(&cnt[q], 1);
                    if (pos < CAP)
                        buf[q][pos] =
                            ((unsigned long long)__float_as_uint(fmaxf(d2a, 0.0f)) << 32)
                            | (unsigned int)(2 * jpair);
                }
                if (d2b <= Tq[q]) {
                    const int pos = atomicAdd(&cnt[q], 1);
                    if (pos < CAP)
                        buf[q][pos] =
                            ((unsigned long long)__float_as_uint(fmaxf(d2b, 0.0f)) << 32)
                            | (unsigned int)(2 * jpair + 1);
                }
            }
        }
    }
    __syncthreads();

    // ---- Wave w: select the 6 smallest keys for query w ----
    const unsigned long long INF64 = ~0ull;
    const int n = min(cnt[wave], CAP);
    unsigned long long a  = (lane      < n) ? buf[wave][lane]      : INF64;
    unsigned long long b2 = (lane + 64 < n) ? buf[wave][lane + 64] : INF64;
    if (b2 < a) { unsigned long long t = a; a = b2; b2 = t; }

    unsigned int myj = 0;
    int active = 0;
    #pragma unroll
    for (int t = 0; t < KNN + 1; ++t) {
        unsigned long long m = a;
        #pragma unroll
        for (int d = 1; d < 64; d <<= 1) {
            const unsigned long long x = shfl_xor_u64(m, d);
            if (x < m) m = x;
        }
        if (a == m) { a = b2; b2 = INF64; }   // keys unique -> one lane drops
        if (t >= 1 && lane == t) { myj = (unsigned int)m; active = 1; }
    }

    // ---- Lanes 1..5 of wave w: neighbor norms for query qbase+w ----
    float nrm = 0.0f;
    if (active) {
        const float4* oi = (const float4*)(outputs + (size_t)(qbase + wave) * CH);
        const float4* oj = (const float4*)(outputs + (size_t)myj * CH);
        float s = 0.0f;
        #pragma unroll
        for (int c = 0; c < 4; ++c) {
            const float4 x = oi[c], y = oj[c];
            const float dx = x.x - y.x, dy = x.y - y.y;
            const float dz = x.z - y.z, dw = x.w - y.w;
            s += dx * dx + dy * dy + dz * dz + dw * dw;
        }
        nrm = sqrtf(s);
    }
    #pragma unroll
    for (int d = 1; d < 64; d <<= 1) nrm += __shfl_xor(nrm, d, 64);

    if (lane == 0) red[wave] = nrm;
    __syncthreads();
    if (tid == 0) {
        float s = 0.0f;
        #pragma unroll
        for (int wv = 0; wv < QPB; ++wv) s += red[wv];
        partial[blockIdx.x] = s;
    }
}

__global__ __launch_bounds__(256) void finalize_kernel(
        const float* __restrict__ partial, float* __restrict__ out) {
    double s = 0.0;
    for (int idx = threadIdx.x; idx < NBLK; idx += 256) s += (double)partial[idx];
    #pragma unroll
    for (int d = 1; d < 64; d <<= 1) s += __shfl_xor(s, d, 64);
    __shared__ double lds[4];
    const int wave = threadIdx.x >> 6;
    const int lane = threadIdx.x & 63;
    if (lane == 0) lds[wave] = s;
    __syncthreads();
    if (threadIdx.x == 0)
        out[0] = (float)((lds[0] + lds[1] + lds[2] + lds[3]) /
                         (double)((long long)NPTS * KNN));
}

extern "C" void kernel_launch(void* const* d_in, const int* in_sizes, int n_in,
                              void* d_out, int out_size, void* d_ws, size_t ws_size,
                              hipStream_t stream) {
    const float* outputs = (const float*)d_in[0];   // (8192, 16) f32
    const float* points  = (const float*)d_in[1];   // (8192, 2)  f32
    float* partial = (float*)d_ws;                  // NBLK floats of scratch
    float* out = (float*)d_out;

    knn_loss_kernel<<<NBLK, THREADS, 0, stream>>>(outputs, points, partial);
    finalize_kernel<<<1, 256, 0, stream>>>(partial, out);
}

// Round 9
// 85.060 us; speedup vs baseline: 1.4847x; 1.4847x over previous
//
#include <hip/hip_runtime.h>

// GeometricLoss: N=8192 2-D points, C=16 outputs, k=5 nearest neighbors,
// result = mean over (i, 5 NN j) of ||outputs[i]-outputs[j]||_2.
//
// Round-9: round-8 structure (512 thr/block, QPB=8, candidates register-
// resident so pass 2 needs no memory) with the launch-bounds spill fixed:
// __launch_bounds__(512, 4) -> VGPR cap 128 (was 64, which spilled p[] to
// scratch: 267 MB of HBM traffic, round 8's regression). 16 waves/CU is
// ample for an ALU-dominated kernel with no steady-state memory.
//
// Pass 1: per-thread per-query min of RAW d2 (min3 folding) over the
// thread's 8 register-held float4 (16 candidates). Clamped minima -> LDS;
// wave w computes T_w = 6th-distinct-smallest of 64 lane pre-mins (lane
// pre-min spans 8 threads' disjoint candidate subsets -> >=6 candidates
// <= T_w guaranteed). Pass 2: recompute d2 from registers with the
// IDENTICAL fmaf sequence (bit-exact vs pass 1), collect (clamped-d2, j)
// u64 keys ((bits<<32)|j) into per-query LDS buffers on the rare hit.
// Select: wave w extracts the 6 smallest keys for query w (replicates
// top_k's smaller-index tie-break), drops the first (self), lanes 1..5
// compute the 16-channel neighbor norms.

static constexpr int NPTS    = 8192;
static constexpr int KNN     = 5;
static constexpr int CH      = 16;
static constexpr int QPB     = 8;                 // queries per block (= waves)
static constexpr int THREADS = 512;
static constexpr int NBLK    = NPTS / QPB;        // 1024 blocks
static constexpr int CAP     = 128;               // per-query candidate buffer
static constexpr int NF4     = NPTS / 2;          // 4096 float4 = 2 points each
static constexpr int ITERS   = NF4 / THREADS;     // 8 float4 per thread

__device__ __forceinline__ unsigned long long shfl_xor_u64(unsigned long long v, int m) {
    unsigned int lo = (unsigned int)v;
    unsigned int hi = (unsigned int)(v >> 32);
    lo = __shfl_xor(lo, m, 64);
    hi = __shfl_xor(hi, m, 64);
    return ((unsigned long long)hi << 32) | lo;
}

__device__ __forceinline__ float rfl(float x) {   // force block-uniform -> SGPR
    return __uint_as_float(__builtin_amdgcn_readfirstlane(__float_as_uint(x)));
}

__global__ __launch_bounds__(512, 4) void knn_loss_kernel(
        const float* __restrict__ outputs,
        const float* __restrict__ points,
        float* __restrict__ partial) {
    const int tid   = threadIdx.x;
    const int wave  = tid >> 6;
    const int lane  = tid & 63;
    const int qbase = blockIdx.x * QPB;

    const float2* __restrict__ pts2 = (const float2*)points;
    const float4* __restrict__ pts4 = (const float4*)points;
    const float FINF = __int_as_float(0x7f800000);

    float pix[QPB], piy[QPB];
    #pragma unroll
    for (int q = 0; q < QPB; ++q) {
        const float2 pq = pts2[qbase + q];
        pix[q] = rfl(pq.x); piy[q] = rfl(pq.y);
    }

    // ---- Load this thread's 8 candidate float4 ONCE; keep live in VGPRs ----
    float4 p[ITERS];
    #pragma unroll
    for (int u = 0; u < ITERS; ++u)
        p[u] = pts4[u * THREADS + tid];

    // ---- Pass 1: per-thread per-query min of raw d2 (branchless min3) ----
    float acc[QPB];
    #pragma unroll
    for (int q = 0; q < QPB; ++q) acc[q] = FINF;
    #pragma unroll
    for (int u = 0; u < ITERS; ++u) {
        #pragma unroll
        for (int q = 0; q < QPB; ++q) {
            const float dxa = pix[q] - p[u].x, dya = piy[q] - p[u].y;
            const float dxb = pix[q] - p[u].z, dyb = piy[q] - p[u].w;
            const float d2a = fmaf(dxa, dxa, dya * dya);
            const float d2b = fmaf(dxb, dxb, dyb * dyb);
            acc[q] = fminf(fminf(acc[q], d2a), d2b);   // v_min3
        }
    }

    // ---- Block thresholds: T_q = 6th-distinct-smallest of 64 lane pre-mins ----
    __shared__ float thrmin[QPB][THREADS];
    __shared__ unsigned long long buf[QPB][CAP];
    __shared__ int cnt[QPB];
    __shared__ float Ts[QPB];
    __shared__ float red[QPB];

    #pragma unroll
    for (int q = 0; q < QPB; ++q)
        thrmin[q][tid] = fmaxf(acc[q], 0.0f);          // clamped per-thread min
    if (tid < QPB) cnt[tid] = 0;
    __syncthreads();

    {   // wave w handles query w; stride-64 reads are bank-conflict-free
        float v = thrmin[wave][lane];
        #pragma unroll
        for (int r = 1; r < THREADS / 64; ++r)
            v = fminf(v, thrmin[wave][lane + r * 64]);
        float T = 0.0f;
        #pragma unroll
        for (int t = 0; t < KNN + 1; ++t) {
            float m = v;
            #pragma unroll
            for (int d = 1; d < 64; d <<= 1) m = fminf(m, __shfl_xor(m, d, 64));
            if (v == m) v = FINF;
            T = m;
        }
        if (lane == 0) Ts[wave] = T;
    }
    __syncthreads();

    float Tq[QPB];
    #pragma unroll
    for (int q = 0; q < QPB; ++q) Tq[q] = rfl(Ts[q]);  // SGPR

    // ---- Pass 2: pure-register recompute, rare per-query collect ----
    #pragma unroll
    for (int u = 0; u < ITERS; ++u) {
        const int jpair = u * THREADS + tid;           // float4 index
        #pragma unroll
        for (int q = 0; q < QPB; ++q) {
            const float dxa = pix[q] - p[u].x, dya = piy[q] - p[u].y;
            const float dxb = pix[q] - p[u].z, dyb = piy[q] - p[u].w;
            const float d2a = fmaf(dxa, dxa, dya * dya);
            const float d2b = fmaf(dxb, dxb, dyb * dyb);
            if (fminf(d2a, d2b) <= Tq[q]) {            // rare: execz skip
                if (d2a <= Tq[q]) {
                    const int pos = atomicAdd(&cnt[q], 1);
                    if (pos < CAP)
                        buf[q][pos] =
                            ((unsigned long long)__float_as_uint(fmaxf(d2a, 0.0f)) << 32)
                            | (unsigned int)(2 * jpair);
                }
                if (d2b <= Tq[q]) {
                    const int pos = atomicAdd(&cnt[q], 1);
                    if (pos < CAP)
                        buf[q][pos] =
                            ((unsigned long long)__float_as_uint(fmaxf(d2b, 0.0f)) << 32)
                            | (unsigned int)(2 * jpair + 1);
                }
            }
        }
    }
    __syncthreads();

    // ---- Wave w: select the 6 smallest keys for query w ----
    const unsigned long long INF64 = ~0ull;
    const int n = min(cnt[wave], CAP);
    unsigned long long a  = (lane      < n) ? buf[wave][lane]      : INF64;
    unsigned long long b2 = (lane + 64 < n) ? buf[wave][lane + 64] : INF64;
    if (b2 < a) { unsigned long long t = a; a = b2; b2 = t; }

    unsigned int myj = 0;
    int active = 0;
    #pragma unroll
    for (int t = 0; t < KNN + 1; ++t) {
        unsigned long long m = a;
        #pragma unroll
        for (int d = 1; d < 64; d <<= 1) {
            const unsigned long long x = shfl_xor_u64(m, d);
            if (x < m) m = x;
        }
        if (a == m) { a = b2; b2 = INF64; }   // keys unique -> one lane drops
        if (t >= 1 && lane == t) { myj = (unsigned int)m; active = 1; }
    }

    // ---- Lanes 1..5 of wave w: neighbor norms for query qbase+w ----
    float nrm = 0.0f;
    if (active) {
        const float4* oi = (const float4*)(outputs + (size_t)(qbase + wave) * CH);
        const float4* oj = (const float4*)(outputs + (size_t)myj * CH);
        float s = 0.0f;
        #pragma unroll
        for (int c = 0; c < 4; ++c) {
            const float4 x = oi[c], y = oj[c];
            const float dx = x.x - y.x, dy = x.y - y.y;
            const float dz = x.z - y.z, dw = x.w - y.w;
            s += dx * dx + dy * dy + dz * dz + dw * dw;
        }
        nrm = sqrtf(s);
    }
    #pragma unroll
    for (int d = 1; d < 64; d <<= 1) nrm += __shfl_xor(nrm, d, 64);

    if (lane == 0) red[wave] = nrm;
    __syncthreads();
    if (tid == 0) {
        float s = 0.0f;
        #pragma unroll
        for (int wv = 0; wv < QPB; ++wv) s += red[wv];
        partial[blockIdx.x] = s;
    }
}

__global__ __launch_bounds__(256) void finalize_kernel(
        const float* __restrict__ partial, float* __restrict__ out) {
    double s = 0.0;
    for (int idx = threadIdx.x; idx < NBLK; idx += 256) s += (double)partial[idx];
    #pragma unroll
    for (int d = 1; d < 64; d <<= 1) s += __shfl_xor(s, d, 64);
    __shared__ double lds[4];
    const int wave = threadIdx.x >> 6;
    const int lane = threadIdx.x & 63;
    if (lane == 0) lds[wave] = s;
    __syncthreads();
    if (threadIdx.x == 0)
        out[0] = (float)((lds[0] + lds[1] + lds[2] + lds[3]) /
                         (double)((long long)NPTS * KNN));
}

extern "C" void kernel_launch(void* const* d_in, const int* in_sizes, int n_in,
                              void* d_out, int out_size, void* d_ws, size_t ws_size,
                              hipStream_t stream) {
    const float* outputs = (const float*)d_in[0];   // (8192, 16) f32
    const float* points  = (const float*)d_in[1];   // (8192, 2)  f32
    float* partial = (float*)d_ws;                  // NBLK floats of scratch
    float* out = (float*)d_out;

    knn_loss_kernel<<<NBLK, THREADS, 0, stream>>>(outputs, points, partial);
    finalize_kernel<<<1, 256, 0, stream>>>(partial, out);
}